// Round 1
// 511.543 us; speedup vs baseline: 1.1272x; 1.1272x over previous
//
#include <hip/hip_runtime.h>

// ---------------------------------------------------------------------------
// Pipeline:
//  k_prep : wfc[512,64] -> wfcT[64,512]   (k-major, coalesced in fc k-loop)
//           w2[64,32,3] -> w2t[3,32,64]   (o-contiguous, lane-coalesced)
//  kA     : h[v] = mean_j relu(conv3_j(vp[nb1[v,:]]))               [V]
//  kB     : f1[v,o] = h[v-1]*w1[o,0]+h[v]*w1[o,1]+h[v+1]*w1[o,2]+b1 [V,32]
//  kC     : h2[v,c] = mean_j relu(conv3_j(f1[nb2[v,j],c]))          [V,32]
//  kD     : f2[v,o] = sum_{k,c} h2[v-1+k,c]*w2t[k,c,o] + b2[o]      [V,64]
//  kE     : out[v,:] = softmax(f2[v,:] @ wfcT + bfc)                [V,512]
//
// R4 change: kD rewritten. Old kD used 64-thread blocks (1 wave -> 16 wg/CU
// cap -> 51% occupancy) and wave-UNIFORM h2 loads that the compiler lowered
// through the scalar cache; h2 is 12.8MB streaming, so the sKcache thrashed
// and each of the 32 c-iterations serialized on scalar-miss latency
// (143us for a kernel with a 7.8us VALU floor / 6us HBM floor).
// New kD: 256 threads / 32 vertices per block; h2 halo tile [34][32] staged
// into LDS with float4 VECTOR loads; inner loop reads h2 as conflict-free
// LDS broadcasts (float4 per row), w2t stays in L1 via lane-coalesced vector
// loads (separate pipe from LDS). All register arrays compile-time indexed.
// ---------------------------------------------------------------------------

__global__ __launch_bounds__(256) void k_prep(const float* __restrict__ wfc,
                                              const float* __restrict__ w2,
                                              float* __restrict__ wfcT,
                                              float* __restrict__ w2t) {
    int t = blockIdx.x * 256 + threadIdx.x;
    if (t < 512 * 64) {
        int k = t >> 9;
        int s = t & 511;
        wfcT[t] = wfc[s * 64 + k];
    } else {
        int i = t - 512 * 64;
        if (i < 64 * 32 * 3) {
            int o = i / 96;
            int r = i - o * 96;
            int c = r / 3;
            int k = r - c * 3;
            w2t[(k * 32 + c) * 64 + o] = w2[i];
        }
    }
}

// conv1 over neighbor axis: one 32-lane segment per vertex
__global__ __launch_bounds__(256) void kA(const float* __restrict__ vp,
                                          const int* __restrict__ nb1,
                                          const float* __restrict__ wv1,
                                          const float* __restrict__ bv1,
                                          float* __restrict__ h, int V) {
    int t = blockIdx.x * 256 + threadIdx.x;
    int v = t >> 5;
    int j = t & 31;
    if (v >= V) return;
    float g = vp[nb1[v * 32 + j]];
    float gm = __shfl_up(g, 1, 32);
    if (j == 0) gm = 0.0f;
    float gp = __shfl_down(g, 1, 32);
    if (j == 31) gp = 0.0f;
    float c = wv1[0] * gm + wv1[1] * g + wv1[2] * gp + bv1[0];
    c = fmaxf(c, 0.0f);
    #pragma unroll
    for (int off = 16; off; off >>= 1) c += __shfl_xor(c, off, 32);
    if (j == 0) h[v] = c * (1.0f / 32.0f);
}

// vertex-shift 3-tap mix into 32 channels
__global__ __launch_bounds__(256) void kB(const float* __restrict__ h,
                                          const float* __restrict__ w1,
                                          const float* __restrict__ b1,
                                          float* __restrict__ f1, int V) {
    int t = blockIdx.x * 256 + threadIdx.x;
    int v = t >> 5;
    int o = t & 31;
    if (v >= V) return;
    float hm = (v > 0) ? h[v - 1] : 0.0f;
    float h0 = h[v];
    float hp = (v + 1 < V) ? h[v + 1] : 0.0f;
    f1[v * 32 + o] = fmaf(hm, w1[o * 3 + 0],
                     fmaf(h0, w1[o * 3 + 1],
                     fmaf(hp, w1[o * 3 + 2], b1[o])));
}

// conv2: gather 32 neighbor rows (32 ch each) into LDS, 3-tap along j, mean
__global__ __launch_bounds__(256) void kC(const float* __restrict__ f1,
                                          const int* __restrict__ nb2,
                                          const float* __restrict__ wv2,
                                          const float* __restrict__ bv2,
                                          float* __restrict__ h2, int V) {
    __shared__ float lds[8 * 32 * 32];  // [vv][j][c], 32 KB
    int t = threadIdx.x;
    int vbase = blockIdx.x * 8;
    int j = t >> 3;        // 0..31
    int seg = t & 7;       // float4 segment within row
    #pragma unroll
    for (int vv = 0; vv < 8; ++vv) {
        int v = vbase + vv;
        float4 val = make_float4(0.f, 0.f, 0.f, 0.f);
        if (v < V) {
            int idx = nb2[v * 32 + j];
            val = *(const float4*)(f1 + (size_t)idx * 32 + seg * 4);
        }
        *(float4*)(lds + vv * 1024 + j * 32 + seg * 4) = val;
    }
    __syncthreads();
    int vv = t >> 5;       // 0..7
    int c = t & 31;
    int v = vbase + vv;
    const float* L = lds + vv * 1024;
    float w0 = wv2[0], w1_ = wv2[1], w2_ = wv2[2], b = bv2[0];
    float prev = 0.0f, cur = L[c];
    float s = 0.0f;
    #pragma unroll
    for (int jj = 0; jj < 32; ++jj) {
        float nxt = (jj < 31) ? L[(jj + 1) * 32 + c] : 0.0f;
        float cv = fmaf(w0, prev, fmaf(w1_, cur, fmaf(w2_, nxt, b)));
        s += fmaxf(cv, 0.0f);
        prev = cur;
        cur = nxt;
    }
    if (v < V) h2[v * 32 + c] = s * (1.0f / 32.0f);
}

// f2 einsum: 256 threads / 32 vertices per block. h2 halo tile [34][32]
// (rows v0-1 .. v0+32) staged in LDS via float4 vector loads (kills the old
// scalar-cache-miss serialization). Each of the 4 waves owns 8 vertices,
// lane = o. Inner loop: per 4-channel group, 10 float4 LDS broadcasts feed
// 96 FMAs; w2t read as lane-coalesced vector loads (L1-resident, VMEM pipe).
__global__ __launch_bounds__(256) void kD(const float* __restrict__ h2,
                                          const float* __restrict__ w2t,
                                          const float* __restrict__ b2,
                                          float* __restrict__ f2, int V) {
    __shared__ float tile[34 * 32];     // 4.25 KB, rows v0-1 .. v0+32
    int t = threadIdx.x;
    int v0 = blockIdx.x * 32;

    // stage h2 halo: 34 rows x 32 ch = 272 float4
    for (int i = t; i < 272; i += 256) {
        int r = i >> 3;                 // tile row (8 float4 per row)
        int s = i & 7;
        int v = v0 - 1 + r;
        float4 val = make_float4(0.f, 0.f, 0.f, 0.f);
        if (v >= 0 && v < V)
            val = *(const float4*)(h2 + (size_t)v * 32 + s * 4);
        *(float4*)(tile + r * 32 + s * 4) = val;
    }
    __syncthreads();

    int o = t & 63;                     // output channel = lane
    int w = t >> 6;                     // wave id 0..3
    int vb = w * 8;                     // this wave's first vertex (rel. v0)
    float bo = b2[o];
    float acc[8];
    #pragma unroll
    for (int m = 0; m < 8; ++m) acc[m] = bo;

    // acc[m] += tile[vb+m+k][c] * w2t[(k*32+c)*64+o]
    // (tile row vb+m+k == vertex (v0+vb+m)-1+k)
    #pragma unroll
    for (int c4 = 0; c4 < 8; ++c4) {
        float4 hv[10];
        #pragma unroll
        for (int r = 0; r < 10; ++r)
            hv[r] = *(const float4*)(tile + (vb + r) * 32 + c4 * 4);
        #pragma unroll
        for (int k = 0; k < 3; ++k) {
            #pragma unroll
            for (int cc = 0; cc < 4; ++cc) {
                int c = c4 * 4 + cc;
                float wv = w2t[(k * 32 + c) * 64 + o];
                #pragma unroll
                for (int m = 0; m < 8; ++m) {
                    float hval = (cc == 0) ? hv[m + k].x :
                                 (cc == 1) ? hv[m + k].y :
                                 (cc == 2) ? hv[m + k].z : hv[m + k].w;
                    acc[m] = fmaf(hval, wv, acc[m]);
                }
            }
        }
    }
    #pragma unroll
    for (int m = 0; m < 8; ++m) {
        int v = v0 + vb + m;
        if (v < V) f2[(size_t)v * 64 + o] = acc[m];
    }
}

#define REP16(X) X(0) X(1) X(2) X(3) X(4) X(5) X(6) X(7) \
                 X(8) X(9) X(10) X(11) X(12) X(13) X(14) X(15)

// fc + softmax: 128 threads, 16 vertices/block, thread owns 4 consecutive
// outputs (float4-coalesced wfcT loads). Accumulators are 16 NAMED float4
// registers (macro-expanded) — no alloca, nothing for SROA to miss.
__global__ __launch_bounds__(128, 2) void kE(const float* __restrict__ f2,
                                             const float* __restrict__ wfcT,
                                             const float* __restrict__ bfc,
                                             float* __restrict__ out, int V) {
    __shared__ float f2s[16 * 64];          // 4 KB
    __shared__ float redmax[2][16];
    __shared__ float redsum[2][16];
    int t = threadIdx.x;
    int wid = t >> 6, lane = t & 63;
    int vbase = blockIdx.x * 16;
    int nv = V - vbase; if (nv > 16) nv = 16;

    for (int i = t; i < 256; i += 128) {    // 256 float4 = 16*64 floats
        float4 val = make_float4(0.f, 0.f, 0.f, 0.f);
        if (i < nv * 16) val = ((const float4*)(f2 + (size_t)vbase * 64))[i];
        ((float4*)f2s)[i] = val;
    }
    __syncthreads();

    int s0 = t * 4;
    float4 bv = *(const float4*)(bfc + s0);

#define KE_DECL(m) float4 A##m = bv;
    REP16(KE_DECL)
#undef KE_DECL

    for (int k = 0; k < 64; k += 4) {
        float4 w0 = *(const float4*)(wfcT + (k + 0) * 512 + s0);
        float4 w1 = *(const float4*)(wfcT + (k + 1) * 512 + s0);
        float4 w2 = *(const float4*)(wfcT + (k + 2) * 512 + s0);
        float4 w3 = *(const float4*)(wfcT + (k + 3) * 512 + s0);
#define KE_FMA(m) { \
        float4 f = *(const float4*)(f2s + m * 64 + k); \
        A##m.x = fmaf(f.x, w0.x, fmaf(f.y, w1.x, fmaf(f.z, w2.x, fmaf(f.w, w3.x, A##m.x)))); \
        A##m.y = fmaf(f.x, w0.y, fmaf(f.y, w1.y, fmaf(f.z, w2.y, fmaf(f.w, w3.y, A##m.y)))); \
        A##m.z = fmaf(f.x, w0.z, fmaf(f.y, w1.z, fmaf(f.z, w2.z, fmaf(f.w, w3.z, A##m.z)))); \
        A##m.w = fmaf(f.x, w0.w, fmaf(f.y, w1.w, fmaf(f.z, w2.w, fmaf(f.w, w3.w, A##m.w)))); }
        REP16(KE_FMA)
#undef KE_FMA
    }

    // softmax over 512 per vertex: wave-reduce then 2-wave combine via LDS
#define KE_MAX(m) { \
        float lm = fmaxf(fmaxf(A##m.x, A##m.y), fmaxf(A##m.z, A##m.w)); \
        lm = fmaxf(lm, __shfl_xor(lm, 32)); \
        lm = fmaxf(lm, __shfl_xor(lm, 16)); \
        lm = fmaxf(lm, __shfl_xor(lm, 8)); \
        lm = fmaxf(lm, __shfl_xor(lm, 4)); \
        lm = fmaxf(lm, __shfl_xor(lm, 2)); \
        lm = fmaxf(lm, __shfl_xor(lm, 1)); \
        if (lane == 0) redmax[wid][m] = lm; }
    REP16(KE_MAX)
#undef KE_MAX
    __syncthreads();

#define KE_EXP(m) { \
        float gm = fmaxf(redmax[0][m], redmax[1][m]); \
        A##m.x = __expf(A##m.x - gm); \
        A##m.y = __expf(A##m.y - gm); \
        A##m.z = __expf(A##m.z - gm); \
        A##m.w = __expf(A##m.w - gm); \
        float ls = (A##m.x + A##m.y) + (A##m.z + A##m.w); \
        ls += __shfl_xor(ls, 32); \
        ls += __shfl_xor(ls, 16); \
        ls += __shfl_xor(ls, 8); \
        ls += __shfl_xor(ls, 4); \
        ls += __shfl_xor(ls, 2); \
        ls += __shfl_xor(ls, 1); \
        if (lane == 0) redsum[wid][m] = ls; }
    REP16(KE_EXP)
#undef KE_EXP
    __syncthreads();

#define KE_STORE(m) if (m < nv) { \
        float inv = 1.0f / (redsum[0][m] + redsum[1][m]); \
        *(float4*)(out + (size_t)(vbase + m) * 512 + s0) = \
            make_float4(A##m.x * inv, A##m.y * inv, A##m.z * inv, A##m.w * inv); }
    REP16(KE_STORE)
#undef KE_STORE
}

extern "C" void kernel_launch(void* const* d_in, const int* in_sizes, int n_in,
                              void* d_out, int out_size, void* d_ws, size_t ws_size,
                              hipStream_t stream) {
    (void)n_in; (void)out_size; (void)ws_size;
    const float* vp  = (const float*)d_in[0];
    const int*   nb1 = (const int*)d_in[1];
    const int*   nb2 = (const int*)d_in[2];
    const float* wv1 = (const float*)d_in[3];
    const float* bv1 = (const float*)d_in[4];
    const float* w1  = (const float*)d_in[5];
    const float* b1  = (const float*)d_in[6];
    const float* wv2 = (const float*)d_in[7];
    const float* bv2 = (const float*)d_in[8];
    const float* w2  = (const float*)d_in[9];
    const float* b2  = (const float*)d_in[10];
    const float* wfc = (const float*)d_in[11];
    const float* bfc = (const float*)d_in[12];
    float* out = (float*)d_out;
    const int V = in_sizes[0];

    float* ws = (float*)d_ws;
    size_t off = 0;
    float* h    = ws + off; off += (size_t)V;
    float* f1   = ws + off; off += (size_t)V * 32;
    float* h2   = ws + off; off += (size_t)V * 32;
    float* f2   = ws + off; off += (size_t)V * 64;
    float* wfcT = ws + off; off += 512 * 64;
    float* w2t  = ws + off; off += 3 * 32 * 64;

    k_prep<<<(512 * 64 + 64 * 32 * 3 + 255) / 256, 256, 0, stream>>>(wfc, w2, wfcT, w2t);
    kA<<<(V * 32 + 255) / 256, 256, 0, stream>>>(vp, nb1, wv1, bv1, h, V);
    kB<<<(V * 32 + 255) / 256, 256, 0, stream>>>(h, w1, b1, f1, V);
    kC<<<(V + 7) / 8, 256, 0, stream>>>(f1, nb2, wv2, bv2, h2, V);
    kD<<<(V + 31) / 32, 256, 0, stream>>>(h2, w2t, b2, f2, V);
    kE<<<(V + 15) / 16, 128, 0, stream>>>(f2, wfcT, bfc, out, V);
}